// Round 23
// baseline (254.646 us; speedup 1.0000x reference)
//
#include <hip/hip_runtime.h>
#include <hip/hip_bf16.h>
#include <stdint.h>

#define B_    4
#define S_    2048
#define D_    1024
#define H_    16
#define DH_   64
#define M_TOT 8192      // B*S
#define NQKV  3072      // 3*H*DH
#define HDH   1024      // H*DH

typedef __bf16 bf16_t;
typedef bf16_t bf16x8 __attribute__((ext_vector_type(8)));
typedef float  f32x4  __attribute__((ext_vector_type(4)));
typedef float  f32x16 __attribute__((ext_vector_type(16)));

// scale folded into Q at QKV epilogue: 1/sqrt(64) * log2(e)
#define QSCALE 0.1803368801111204f

__device__ __forceinline__ short f2bf(float f) {
  union { float f; uint32_t u; } x; x.f = f;
  uint32_t r = (x.u + 0x7fffu + ((x.u >> 16) & 1u)) >> 16;
  return (short)(uint16_t)r;
}

__device__ __forceinline__ uint32_t cvt_pk_bf16(float lo, float hi) {
  uint32_t r;
  asm("v_cvt_pk_bf16_f32 %0, %1, %2" : "=v"(r) : "v"(lo), "v"(hi));
  return r;
}

// d' = {d.lo, s.lo}, s' = {d.hi, s.hi}
__device__ __forceinline__ void permlane32_swap(uint32_t& d, uint32_t& s) {
  asm("v_permlane32_swap_b32 %0, %1" : "+v"(d), "+v"(s));
}

#define ASYNC_COPY16(g, l) \
  __builtin_amdgcn_global_load_lds((const __attribute__((address_space(1))) void*)(g), \
                                   (__attribute__((address_space(3))) void*)(l), 16, 0, 0)

// ---------------- prep kernels ----------------

__global__ __launch_bounds__(256) void k_cvt(const float* __restrict__ in, short* __restrict__ out, int n4) {
  int i = blockIdx.x * 256 + threadIdx.x;
  if (i < n4) {
    float4 v = ((const float4*)in)[i];
    short4 o;
    o.x = f2bf(v.x); o.y = f2bf(v.y); o.z = f2bf(v.z); o.w = f2bf(v.w);
    ((short4*)out)[i] = o;
  }
}

// LDS-tiled transpose: in (R,C) f32 row-major -> out (C,R) bf16 row-major.
__global__ __launch_bounds__(256) void k_transpose_t(const float* __restrict__ in, short* __restrict__ out,
                                                     int R, int C) {
  __shared__ short t[32][33];
  const int bx = blockIdx.x * 32;
  const int by = blockIdx.y * 32;
  const int tid = threadIdx.x;
  const int row = tid >> 3, c4 = (tid & 7) * 4;
  const float4 v = *(const float4*)&in[(size_t)(by + row) * C + bx + c4];
  t[row][c4 + 0] = f2bf(v.x); t[row][c4 + 1] = f2bf(v.y);
  t[row][c4 + 2] = f2bf(v.z); t[row][c4 + 3] = f2bf(v.w);
  __syncthreads();
  short4 o;
  o.x = t[c4 + 0][row]; o.y = t[c4 + 1][row];
  o.z = t[c4 + 2][row]; o.w = t[c4 + 3][row];
  *(short4*)&out[(size_t)(bx + row) * R + by + c4] = o;
}

// ---------------- GEMM core: C = A(row-major MxK) * Bt(row-major NxK)^T ----------------
// Round-13 proven 2-barrier BK=32 structure.

__device__ __forceinline__ void gemm_core(const short* __restrict__ A,
                                          const short* __restrict__ Bt,
                                          int row0, int col0, int K,
                                          short* lA, short* lB,
                                          f32x4 acc[4][4]) {
  const int tid  = threadIdx.x;
  const int wave = tid >> 6, lane = tid & 63;
  const int wr = wave >> 1, wc = wave & 1;
  const int stg_r = lane >> 2;
  const int stg_k = (lane & 3) * 8;
  const int fr = lane & 15;
  const int fk = (lane >> 4) * 8;

  for (int k0 = 0; k0 < K; k0 += 32) {
    __syncthreads();
#pragma unroll
    for (int c = 0; c < 2; ++c) {
      const int seg = wave * 2 + c;
      const short* ga = A  + (size_t)(row0 + seg * 16 + stg_r) * K + (k0 + stg_k);
      const short* gb = Bt + (size_t)(col0 + seg * 16 + stg_r) * K + (k0 + stg_k);
      ASYNC_COPY16(ga, lA + seg * 512);
      ASYNC_COPY16(gb, lB + seg * 512);
    }
    __syncthreads();
    bf16x8 af[4], bfr[4];
#pragma unroll
    for (int m = 0; m < 4; ++m)
      af[m] = *(const bf16x8*)(lA + (wr * 64 + m * 16 + fr) * 32 + fk);
#pragma unroll
    for (int n = 0; n < 4; ++n)
      bfr[n] = *(const bf16x8*)(lB + (wc * 64 + n * 16 + fr) * 32 + fk);
#pragma unroll
    for (int m = 0; m < 4; ++m)
#pragma unroll
      for (int n = 0; n < 4; ++n)
        acc[m][n] = __builtin_amdgcn_mfma_f32_16x16x32_bf16(af[m], bfr[n], acc[m][n], 0, 0, 0);
  }
}

// QKV GEMM. t = col0>>10 is BLOCK-UNIFORM (col0 multiple of 128). Epilogue:
//   t==2 (V): direct short4 stores (r -> s contiguous) -- r18 proven path.
//   t<2 (Q/K): LDS-transposed coalesced stores. The 128x128 bf16 tile is
//   staged through the 16KB staging LDS in two 64-col passes (XOR-swizzled
//   8-short chunks), then 256 threads each write 4x16B contiguous (full
//   128B [s][e] rows). Bias (+QSCALE for Q) applied before staging.
__global__ __launch_bounds__(256) void k_gemm_qkv(const short* __restrict__ A, const short* __restrict__ Bt,
                                                  const float* __restrict__ bias,
                                                  short* __restrict__ Qb, short* __restrict__ Kb,
                                                  short* __restrict__ Vt) {
  __shared__ short lsh[2 * 128 * 32];
  f32x4 acc[4][4];
#pragma unroll
  for (int m = 0; m < 4; ++m)
#pragma unroll
    for (int n = 0; n < 4; ++n)
      acc[m][n] = (f32x4){0.f, 0.f, 0.f, 0.f};
  const int row0 = blockIdx.x * 128, col0 = blockIdx.y * 128;
  gemm_core(A, Bt, row0, col0, D_, lsh, lsh + 128 * 32, acc);
  const int tid = threadIdx.x;
  const int lane = tid & 63, wave = tid >> 6;
  const int wr = wave >> 1, wc = wave & 1;
  const int tq = col0 >> 10;               // block-uniform output tensor id

  if (tq == 2) {
    // ---- V third: direct short4 path (proven) ----
#pragma unroll
    for (int m = 0; m < 4; ++m) {
      const int rbase = row0 + wr * 64 + m * 16 + (lane >> 4) * 4;
      const int bb = rbase >> 11, s0 = rbase & 2047;
#pragma unroll
      for (int n = 0; n < 4; ++n) {
        const int col = col0 + wc * 64 + n * 16 + (lane & 15);
        const float bv = bias[col];
        const int rem = col & 1023, hh = rem >> 6, e = rem & 63;
        short4 o;
        o.x = f2bf(acc[m][n][0] + bv);
        o.y = f2bf(acc[m][n][1] + bv);
        o.z = f2bf(acc[m][n][2] + bv);
        o.w = f2bf(acc[m][n][3] + bv);
        *(short4*)&Vt[((size_t)(bb * H_ + hh) * DH_ + e) * S_ + s0] = o;
      }
    }
  } else {
    // ---- Q/K thirds: LDS-transposed coalesced epilogue ----
    short* dst = (tq == 0) ? Qb : Kb;
    const float scl = (tq == 0) ? QSCALE : 1.0f;
    const int bb = row0 >> 11, sBase = row0 & 2047;
#pragma unroll 1
    for (int pass = 0; pass < 2; ++pass) {
      __syncthreads();                     // staging LDS free (covers gemm_core reads too)
      if (wc == pass) {
#pragma unroll
        for (int m = 0; m < 4; ++m) {
          const int rl = wr * 64 + m * 16 + (lane >> 4) * 4;
#pragma unroll
          for (int n = 0; n < 4; ++n) {
            const int cl = n * 16 + (lane & 15);        // 0..63 within pass
            const float bv = bias[col0 + pass * 64 + cl];
#pragma unroll
            for (int r = 0; r < 4; ++r) {
              const int rloc = rl + r;
              const int sc = (((cl >> 3) ^ (rloc & 7)) << 3) | (cl & 7);
              lsh[rloc * 64 + sc] = f2bf((acc[m][n][r] + bv) * scl);
            }
          }
        }
      }
      __syncthreads();
      const int rloc = tid >> 1, seg = tid & 1;
      const int hh = ((col0 + pass * 64) & 1023) >> 6;
      short* gp = dst + ((size_t)(bb * H_ + hh) * S_ + sBase + rloc) * DH_ + seg * 32;
#pragma unroll
      for (int k = 0; k < 4; ++k) {
        const int chunk = (seg * 4 + k) ^ (rloc & 7);
        *(int4*)(gp + k * 8) = *(const int4*)&lsh[rloc * 64 + chunk * 8];
      }
    }
  }
}

// Output GEMM: out f32 + bias. 2-D grid (64, 8).
__global__ __launch_bounds__(256) void k_gemm_out(const short* __restrict__ A, const short* __restrict__ Bt,
                                                  const float* __restrict__ bias, float* __restrict__ C) {
  __shared__ short lA[128 * 32];
  __shared__ short lB[128 * 32];
  f32x4 acc[4][4];
#pragma unroll
  for (int m = 0; m < 4; ++m)
#pragma unroll
    for (int n = 0; n < 4; ++n)
      acc[m][n] = (f32x4){0.f, 0.f, 0.f, 0.f};
  const int row0 = blockIdx.x * 128, col0 = blockIdx.y * 128;
  gemm_core(A, Bt, row0, col0, HDH, lA, lB, acc);
  const int lane = threadIdx.x & 63, wave = threadIdx.x >> 6;
  const int wr = wave >> 1, wc = wave & 1;
#pragma unroll
  for (int m = 0; m < 4; ++m) {
    const int rbase = row0 + wr * 64 + m * 16 + (lane >> 4) * 4;
#pragma unroll
    for (int n = 0; n < 4; ++n) {
      const int col = col0 + wc * 64 + n * 16 + (lane & 15);
      const float bv = bias[col];
#pragma unroll
      for (int r = 0; r < 4; ++r)
        C[(size_t)(rbase + r) * D_ + col] = acc[m][n][r] + bv;
    }
  }
}

// ---------------- flash attention (round-18 banked: dual Q-stream + setprio) ----------------

template <bool MASKED>
__device__ __forceinline__ void softmax_pack(const f32x16& sacc, int ql, int hi,
                                             f32x16& o0, f32x16& o1,
                                             float& m, float& lsum,
                                             bf16x8& pb0v, bf16x8& pb1v) {
  float p[16];
#pragma unroll
  for (int r = 0; r < 16; ++r) {
    float s = sacc[r];
    if (MASKED) {
      const int kl = (r & 3) + 8 * (r >> 2) + 4 * hi;
      s = (kl <= ql) ? s : -1.0e30f;
    }
    p[r] = s;
  }
  float t0 = fmaxf(fmaxf(p[0], p[1]), p[2]);
  float t1 = fmaxf(fmaxf(p[3], p[4]), p[5]);
  float t2 = fmaxf(fmaxf(p[6], p[7]), p[8]);
  float t3 = fmaxf(fmaxf(p[9], p[10]), p[11]);
  float t4 = fmaxf(fmaxf(p[12], p[13]), p[14]);
  float pmax = fmaxf(fmaxf(fmaxf(t0, t1), t2), fmaxf(fmaxf(t3, t4), p[15]));
  if (__any(pmax - m > 8.0f)) {           // T13 defer-max (rare)
    const float pmr = fmaxf(pmax, __shfl_xor(pmax, 32));
    const float mn = fmaxf(m, pmr);
    const float al = __builtin_amdgcn_exp2f(m - mn);
    lsum *= al;
#pragma unroll
    for (int r = 0; r < 16; ++r) { o0[r] *= al; o1[r] *= al; }
    m = mn;
  }
#pragma unroll
  for (int r = 0; r < 16; ++r) p[r] = __builtin_amdgcn_exp2f(p[r] - m);
  {
    float s0 = (p[0] + p[1]) + (p[2] + p[3]);
    float s1 = (p[4] + p[5]) + (p[6] + p[7]);
    float s2 = (p[8] + p[9]) + (p[10] + p[11]);
    float s3 = (p[12] + p[13]) + (p[14] + p[15]);
    lsum += (s0 + s1) + (s2 + s3);
  }
  uint32_t A0 = cvt_pk_bf16(p[0],  p[1]);
  uint32_t A1 = cvt_pk_bf16(p[2],  p[3]);
  uint32_t B0 = cvt_pk_bf16(p[4],  p[5]);
  uint32_t B1 = cvt_pk_bf16(p[6],  p[7]);
  uint32_t A2 = cvt_pk_bf16(p[8],  p[9]);
  uint32_t A3 = cvt_pk_bf16(p[10], p[11]);
  uint32_t B2 = cvt_pk_bf16(p[12], p[13]);
  uint32_t B3 = cvt_pk_bf16(p[14], p[15]);
  permlane32_swap(A0, B0);
  permlane32_swap(A1, B1);
  permlane32_swap(A2, B2);
  permlane32_swap(A3, B3);
  union { uint32_t u[4]; bf16x8 v; } pb0, pb1;
  pb0.u[0] = A0; pb0.u[1] = A1; pb0.u[2] = B0; pb0.u[3] = B1;
  pb1.u[0] = A2; pb1.u[1] = A3; pb1.u[2] = B2; pb1.u[3] = B3;
  pb0v = pb0.v; pb1v = pb1.v;
}

// single-stream tile (used for stream B's solo diagonal)
template <bool MASKED>
__device__ __forceinline__ void attn_tile(int kt, int ql, int hi,
                                          const short* __restrict__ Kp,
                                          const short* __restrict__ Vp,
                                          const bf16x8 qf[4],
                                          f32x16& oacc0, f32x16& oacc1,
                                          float& m, float& lsum) {
  const short* kb = Kp + (size_t)(kt + ql) * DH_ + hi * 8;
  bf16x8 kf0 = *(const bf16x8*)(kb);
  bf16x8 kf1 = *(const bf16x8*)(kb + 16);
  bf16x8 kf2 = *(const bf16x8*)(kb + 32);
  bf16x8 kf3 = *(const bf16x8*)(kb + 48);
  const short* vb0 = Vp + (size_t)(ql) * S_ + kt + hi * 8;
  const short* vb1 = Vp + (size_t)(32 + ql) * S_ + kt + hi * 8;
  bf16x8 vf00 = *(const bf16x8*)(vb0);
  bf16x8 vf01 = *(const bf16x8*)(vb0 + 16);
  bf16x8 vf10 = *(const bf16x8*)(vb1);
  bf16x8 vf11 = *(const bf16x8*)(vb1 + 16);

  f32x16 sacc;
#pragma unroll
  for (int r = 0; r < 16; ++r) sacc[r] = 0.f;
  __builtin_amdgcn_s_setprio(1);
  sacc = __builtin_amdgcn_mfma_f32_32x32x16_bf16(kf0, qf[0], sacc, 0, 0, 0);
  sacc = __builtin_amdgcn_mfma_f32_32x32x16_bf16(kf1, qf[1], sacc, 0, 0, 0);
  sacc = __builtin_amdgcn_mfma_f32_32x32x16_bf16(kf2, qf[2], sacc, 0, 0, 0);
  sacc = __builtin_amdgcn_mfma_f32_32x32x16_bf16(kf3, qf[3], sacc, 0, 0, 0);
  __builtin_amdgcn_s_setprio(0);

  bf16x8 pb0, pb1;
  softmax_pack<MASKED>(sacc, ql, hi, oacc0, oacc1, m, lsum, pb0, pb1);

  __builtin_amdgcn_s_setprio(1);
  oacc0 = __builtin_amdgcn_mfma_f32_32x32x16_bf16(vf00, pb0, oacc0, 0, 0, 0);
  oacc0 = __builtin_amdgcn_mfma_f32_32x32x16_bf16(vf01, pb1, oacc0, 0, 0, 0);
  oacc1 = __builtin_amdgcn_mfma_f32_32x32x16_bf16(vf10, pb0, oacc1, 0, 0, 0);
  oacc1 = __builtin_amdgcn_mfma_f32_32x32x16_bf16(vf11, pb1, oacc1, 0, 0, 0);
  __builtin_amdgcn_s_setprio(0);
}

// dual-stream tile: K/V loaded once, both streams computed (A may be masked)
template <bool MASKA>
__device__ __forceinline__ void attn_tile2(int kt, int ql, int hi,
                                           const short* __restrict__ Kp,
                                           const short* __restrict__ Vp,
                                           const bf16x8 qfA[4], const bf16x8 qfB[4],
                                           f32x16& oA0, f32x16& oA1, float& mA, float& lA,
                                           f32x16& oB0, f32x16& oB1, float& mB, float& lB) {
  const short* kb = Kp + (size_t)(kt + ql) * DH_ + hi * 8;
  bf16x8 kf0 = *(const bf16x8*)(kb);
  bf16x8 kf1 = *(const bf16x8*)(kb + 16);
  bf16x8 kf2 = *(const bf16x8*)(kb + 32);
  bf16x8 kf3 = *(const bf16x8*)(kb + 48);
  const short* vb0 = Vp + (size_t)(ql) * S_ + kt + hi * 8;
  const short* vb1 = Vp + (size_t)(32 + ql) * S_ + kt + hi * 8;
  bf16x8 vf00 = *(const bf16x8*)(vb0);
  bf16x8 vf01 = *(const bf16x8*)(vb0 + 16);
  bf16x8 vf10 = *(const bf16x8*)(vb1);
  bf16x8 vf11 = *(const bf16x8*)(vb1 + 16);

  f32x16 sA, sB;
#pragma unroll
  for (int r = 0; r < 16; ++r) { sA[r] = 0.f; sB[r] = 0.f; }
  __builtin_amdgcn_s_setprio(1);
  sA = __builtin_amdgcn_mfma_f32_32x32x16_bf16(kf0, qfA[0], sA, 0, 0, 0);
  sB = __builtin_amdgcn_mfma_f32_32x32x16_bf16(kf0, qfB[0], sB, 0, 0, 0);
  sA = __builtin_amdgcn_mfma_f32_32x32x16_bf16(kf1, qfA[1], sA, 0, 0, 0);
  sB = __builtin_amdgcn_mfma_f32_32x32x16_bf16(kf1, qfB[1], sB, 0, 0, 0);
  sA = __builtin_amdgcn_mfma_f32_32x32x16_bf16(kf2, qfA[2], sA, 0, 0, 0);
  sB = __builtin_amdgcn_mfma_f32_32x32x16_bf16(kf2, qfB[2], sB, 0, 0, 0);
  sA = __builtin_amdgcn_mfma_f32_32x32x16_bf16(kf3, qfA[3], sA, 0, 0, 0);
  sB = __builtin_amdgcn_mfma_f32_32x32x16_bf16(kf3, qfB[3], sB, 0, 0, 0);
  __builtin_amdgcn_s_setprio(0);

  bf16x8 pA0, pA1, pB0, pB1;
  softmax_pack<MASKA>(sA, ql, hi, oA0, oA1, mA, lA, pA0, pA1);
  softmax_pack<false>(sB, ql, hi, oB0, oB1, mB, lB, pB0, pB1);

  __builtin_amdgcn_s_setprio(1);
  oA0 = __builtin_amdgcn_mfma_f32_32x32x16_bf16(vf00, pA0, oA0, 0, 0, 0);
  oB0 = __builtin_amdgcn_mfma_f32_32x32x16_bf16(vf00, pB0, oB0, 0, 0, 0);
  oA0 = __builtin_amdgcn_mfma_f32_32x32x16_bf16(vf01, pA1, oA0, 0, 0, 0);
  oB0 = __builtin_amdgcn_mfma_f32_32x32x16_bf16(vf01, pB1, oB0, 0, 0, 0);
  oA1 = __builtin_amdgcn_mfma_f32_32x32x16_bf16(vf10, pA0, oA1, 0, 0, 0);
  oB1 = __builtin_amdgcn_mfma_f32_32x32x16_bf16(vf10, pB0, oB1, 0, 0, 0);
  oA1 = __builtin_amdgcn_mfma_f32_32x32x16_bf16(vf11, pA1, oA1, 0, 0, 0);
  oB1 = __builtin_amdgcn_mfma_f32_32x32x16_bf16(vf11, pB1, oB1, 0, 0, 0);
  __builtin_amdgcn_s_setprio(0);
}

__device__ __forceinline__ void write_out(short* __restrict__ att, int b, int h,
                                          int q0, int ql, int hi,
                                          const f32x16& o0, const f32x16& o1, float lsum) {
  lsum += __shfl_xor(lsum, 32);
  const float rl = __builtin_amdgcn_rcpf(lsum);
  short* ob = att + (size_t)((size_t)b * S_ + q0 + ql) * HDH + h * DH_ + 4 * hi;
#pragma unroll
  for (int dt = 0; dt < 2; ++dt) {
#pragma unroll
    for (int a = 0; a < 4; ++a) {
      const int rb = 4 * a;
      float v0 = (dt ? o1[rb + 0] : o0[rb + 0]) * rl;
      float v1 = (dt ? o1[rb + 1] : o0[rb + 1]) * rl;
      float v2 = (dt ? o1[rb + 2] : o0[rb + 2]) * rl;
      float v3 = (dt ? o1[rb + 3] : o0[rb + 3]) * rl;
      short4 o;
      o.x = f2bf(v0); o.y = f2bf(v1); o.z = f2bf(v2); o.w = f2bf(v3);
      *(short4*)(ob + dt * 32 + 8 * a) = o;
    }
  }
}

// 2048 blocks x 64 threads (1 wave/block). Decode: xcd = j&7 -> bh =
// xcd+8*(c&7) (8 bh per XCD, K/V 4MB = L2); s = 31 - (c>>3) so the biggest
// pairs dispatch first and tiny pairs form the drain tail.
__global__ __launch_bounds__(64, 3) void k_attn(const short* __restrict__ Qb, const short* __restrict__ Kb,
                                                const short* __restrict__ Vt, short* __restrict__ att) {
  const int lane = threadIdx.x & 63;
  const int j = blockIdx.x;
  const int xcd = j & 7, c = j >> 3;       // c in [0,256)
  const int bhLo = c & 7;
  const int s = 31 - (c >> 3);             // 31..0, big first
  const int gg = xcd + 8 * bhLo;           // (b,h) id in [0,64)
  const int b = gg >> 4, h = gg & 15;
  const int pA = 2 * s, pB = 2 * s + 1;    // adjacent q-block pair
  const int qA = pA * 32, qB = pB * 32;
  const size_t bh = (size_t)(b * H_ + h);
  const short* Qp = Qb + bh * (S_ * DH_);
  const short* Kp = Kb + bh * (S_ * DH_);
  const short* Vp = Vt + bh * (DH_ * S_);
  const int ql = lane & 31, hi = lane >> 5;

  bf16x8 qfA[4], qfB[4];
#pragma unroll
  for (int ss = 0; ss < 4; ++ss) {
    qfA[ss] = *(const bf16x8*)(Qp + (size_t)(qA + ql) * DH_ + ss * 16 + hi * 8);
    qfB[ss] = *(const bf16x8*)(Qp + (size_t)(qB + ql) * DH_ + ss * 16 + hi * 8);
  }

  f32x16 oA0, oA1, oB0, oB1;
#pragma unroll
  for (int r = 0; r < 16; ++r) { oA0[r] = 0.f; oA1[r] = 0.f; oB0[r] = 0.f; oB1[r] = 0.f; }
  float mA = -3.0e38f, lA = 0.f, mB = -3.0e38f, lB = 0.f;

#pragma unroll 1
  for (int t = 0; t < pA; ++t)
    attn_tile2<false>(t * 32, ql, hi, Kp, Vp, qfA, qfB, oA0, oA1, mA, lA, oB0, oB1, mB, lB);
  attn_tile2<true>(qA, ql, hi, Kp, Vp, qfA, qfB, oA0, oA1, mA, lA, oB0, oB1, mB, lB);
  attn_tile<true>(qB, ql, hi, Kp, Vp, qfB, oB0, oB1, mB, lB);

  write_out(att, b, h, qA, ql, hi, oA0, oA1, lA);
  write_out(att, b, h, qB, ql, hi, oB0, oB1, lB);
}

// ---------------- launcher ----------------

extern "C" void kernel_launch(void* const* d_in, const int* in_sizes, int n_in,
                              void* d_out, int out_size, void* d_ws, size_t ws_size,
                              hipStream_t stream) {
  const float* x     = (const float*)d_in[0];
  const float* w_qkv = (const float*)d_in[1];
  const float* b_qkv = (const float*)d_in[2];
  const float* w_out = (const float*)d_in[3];
  const float* b_out = (const float*)d_in[4];
  float* out = (float*)d_out;

  char* p = (char*)d_ws;
  short* xb    = (short*)p; p += (size_t)M_TOT * D_ * 2;
  short* wqkvT = (short*)p; p += (size_t)NQKV * D_ * 2;
  short* woutT = (short*)p; p += (size_t)D_ * HDH * 2;
  short* Qb    = (short*)p; p += (size_t)B_ * H_ * S_ * DH_ * 2;
  short* Kb    = (short*)p; p += (size_t)B_ * H_ * S_ * DH_ * 2;
  short* Vt    = (short*)p; p += (size_t)B_ * H_ * S_ * DH_ * 2;
  short* att   = (short*)p; p += (size_t)M_TOT * HDH * 2;

  k_cvt<<<M_TOT * D_ / 4 / 256, 256, 0, stream>>>(x, xb, M_TOT * D_ / 4);
  k_transpose_t<<<dim3(NQKV / 32, D_ / 32), 256, 0, stream>>>(w_qkv, wqkvT, D_, NQKV);
  k_transpose_t<<<dim3(D_ / 32, HDH / 32), 256, 0, stream>>>(w_out, woutT, HDH, D_);
  k_gemm_qkv<<<dim3(M_TOT / 128, NQKV / 128), 256, 0, stream>>>(xb, wqkvT, b_qkv, Qb, Kb, Vt);
  k_attn<<<2048, 64, 0, stream>>>(Qb, Kb, Vt, att);
  k_gemm_out<<<dim3(M_TOT / 128, D_ / 128), 256, 0, stream>>>(att, woutT, b_out, out);
}

// Round 24
// 199.086 us; speedup vs baseline: 1.2791x; 1.2791x over previous
//
#include <hip/hip_runtime.h>
#include <hip/hip_bf16.h>
#include <stdint.h>

#define B_    4
#define S_    2048
#define D_    1024
#define H_    16
#define DH_   64
#define M_TOT 8192      // B*S
#define NQKV  3072      // 3*H*DH
#define HDH   1024      // H*DH

typedef __bf16 bf16_t;
typedef bf16_t bf16x8 __attribute__((ext_vector_type(8)));
typedef float  f32x4  __attribute__((ext_vector_type(4)));
typedef float  f32x16 __attribute__((ext_vector_type(16)));

// scale folded into Q at QKV epilogue: 1/sqrt(64) * log2(e)
#define QSCALE 0.1803368801111204f

__device__ __forceinline__ short f2bf(float f) {
  union { float f; uint32_t u; } x; x.f = f;
  uint32_t r = (x.u + 0x7fffu + ((x.u >> 16) & 1u)) >> 16;
  return (short)(uint16_t)r;
}

__device__ __forceinline__ uint32_t cvt_pk_bf16(float lo, float hi) {
  uint32_t r;
  asm("v_cvt_pk_bf16_f32 %0, %1, %2" : "=v"(r) : "v"(lo), "v"(hi));
  return r;
}

// d' = {d.lo, s.lo}, s' = {d.hi, s.hi}
__device__ __forceinline__ void permlane32_swap(uint32_t& d, uint32_t& s) {
  asm("v_permlane32_swap_b32 %0, %1" : "+v"(d), "+v"(s));
}

#define ASYNC_COPY16(g, l) \
  __builtin_amdgcn_global_load_lds((const __attribute__((address_space(1))) void*)(g), \
                                   (__attribute__((address_space(3))) void*)(l), 16, 0, 0)

// ---------------- prep kernels ----------------

__global__ __launch_bounds__(256) void k_cvt(const float* __restrict__ in, short* __restrict__ out, int n4) {
  int i = blockIdx.x * 256 + threadIdx.x;
  if (i < n4) {
    float4 v = ((const float4*)in)[i];
    short4 o;
    o.x = f2bf(v.x); o.y = f2bf(v.y); o.z = f2bf(v.z); o.w = f2bf(v.w);
    ((short4*)out)[i] = o;
  }
}

// LDS-tiled transpose: in (R,C) f32 row-major -> out (C,R) bf16 row-major.
__global__ __launch_bounds__(256) void k_transpose_t(const float* __restrict__ in, short* __restrict__ out,
                                                     int R, int C) {
  __shared__ short t[32][33];
  const int bx = blockIdx.x * 32;
  const int by = blockIdx.y * 32;
  const int tid = threadIdx.x;
  const int row = tid >> 3, c4 = (tid & 7) * 4;
  const float4 v = *(const float4*)&in[(size_t)(by + row) * C + bx + c4];
  t[row][c4 + 0] = f2bf(v.x); t[row][c4 + 1] = f2bf(v.y);
  t[row][c4 + 2] = f2bf(v.z); t[row][c4 + 3] = f2bf(v.w);
  __syncthreads();
  short4 o;
  o.x = t[c4 + 0][row]; o.y = t[c4 + 1][row];
  o.z = t[c4 + 2][row]; o.w = t[c4 + 3][row];
  *(short4*)&out[(size_t)(bx + row) * R + by + c4] = o;
}

// ---------------- GEMM core: C = A(row-major MxK) * Bt(row-major NxK)^T ----------------
// Round-13 proven 2-barrier BK=32 structure.

__device__ __forceinline__ void gemm_core(const short* __restrict__ A,
                                          const short* __restrict__ Bt,
                                          int row0, int col0, int K,
                                          short* lA, short* lB,
                                          f32x4 acc[4][4]) {
  const int tid  = threadIdx.x;
  const int wave = tid >> 6, lane = tid & 63;
  const int wr = wave >> 1, wc = wave & 1;
  const int stg_r = lane >> 2;
  const int stg_k = (lane & 3) * 8;
  const int fr = lane & 15;
  const int fk = (lane >> 4) * 8;

  for (int k0 = 0; k0 < K; k0 += 32) {
    __syncthreads();
#pragma unroll
    for (int c = 0; c < 2; ++c) {
      const int seg = wave * 2 + c;
      const short* ga = A  + (size_t)(row0 + seg * 16 + stg_r) * K + (k0 + stg_k);
      const short* gb = Bt + (size_t)(col0 + seg * 16 + stg_r) * K + (k0 + stg_k);
      ASYNC_COPY16(ga, lA + seg * 512);
      ASYNC_COPY16(gb, lB + seg * 512);
    }
    __syncthreads();
    bf16x8 af[4], bfr[4];
#pragma unroll
    for (int m = 0; m < 4; ++m)
      af[m] = *(const bf16x8*)(lA + (wr * 64 + m * 16 + fr) * 32 + fk);
#pragma unroll
    for (int n = 0; n < 4; ++n)
      bfr[n] = *(const bf16x8*)(lB + (wc * 64 + n * 16 + fr) * 32 + fk);
#pragma unroll
    for (int m = 0; m < 4; ++m)
#pragma unroll
      for (int n = 0; n < 4; ++n)
        acc[m][n] = __builtin_amdgcn_mfma_f32_16x16x32_bf16(af[m], bfr[n], acc[m][n], 0, 0, 0);
  }
}

// QKV GEMM epilogue scatters to Q (scaled), K, Vt with bias add. 2-D grid.
// Vt writes packed as short4 (r -> s contiguous, same bb/hh/e; 8B-aligned).
__global__ __launch_bounds__(256) void k_gemm_qkv(const short* __restrict__ A, const short* __restrict__ Bt,
                                                  const float* __restrict__ bias,
                                                  short* __restrict__ Qb, short* __restrict__ Kb,
                                                  short* __restrict__ Vt) {
  __shared__ short lA[128 * 32];
  __shared__ short lB[128 * 32];
  f32x4 acc[4][4];
#pragma unroll
  for (int m = 0; m < 4; ++m)
#pragma unroll
    for (int n = 0; n < 4; ++n)
      acc[m][n] = (f32x4){0.f, 0.f, 0.f, 0.f};
  const int row0 = blockIdx.x * 128, col0 = blockIdx.y * 128;
  gemm_core(A, Bt, row0, col0, D_, lA, lB, acc);
  const int lane = threadIdx.x & 63, wave = threadIdx.x >> 6;
  const int wr = wave >> 1, wc = wave & 1;
#pragma unroll
  for (int m = 0; m < 4; ++m) {
    const int rbase = row0 + wr * 64 + m * 16 + (lane >> 4) * 4;
    const int bb = rbase >> 11, s0 = rbase & 2047;   // row-quad stays in one b
#pragma unroll
    for (int n = 0; n < 4; ++n) {
      const int col = col0 + wc * 64 + n * 16 + (lane & 15);
      const float bv = bias[col];
      const int t = col >> 10, rem = col & 1023, hh = rem >> 6, e = rem & 63;
      if (t == 2) {
        short4 o;
        o.x = f2bf(acc[m][n][0] + bv);
        o.y = f2bf(acc[m][n][1] + bv);
        o.z = f2bf(acc[m][n][2] + bv);
        o.w = f2bf(acc[m][n][3] + bv);
        *(short4*)&Vt[((size_t)(bb * H_ + hh) * DH_ + e) * S_ + s0] = o;
      } else if (t == 0) {
#pragma unroll
        for (int r = 0; r < 4; ++r)
          Qb[((size_t)(bb * H_ + hh) * S_ + (s0 + r)) * DH_ + e] = f2bf((acc[m][n][r] + bv) * QSCALE);
      } else {
#pragma unroll
        for (int r = 0; r < 4; ++r)
          Kb[((size_t)(bb * H_ + hh) * S_ + (s0 + r)) * DH_ + e] = f2bf(acc[m][n][r] + bv);
      }
    }
  }
}

// Output GEMM: out f32 + bias. 2-D grid (64, 8).
__global__ __launch_bounds__(256) void k_gemm_out(const short* __restrict__ A, const short* __restrict__ Bt,
                                                  const float* __restrict__ bias, float* __restrict__ C) {
  __shared__ short lA[128 * 32];
  __shared__ short lB[128 * 32];
  f32x4 acc[4][4];
#pragma unroll
  for (int m = 0; m < 4; ++m)
#pragma unroll
    for (int n = 0; n < 4; ++n)
      acc[m][n] = (f32x4){0.f, 0.f, 0.f, 0.f};
  const int row0 = blockIdx.x * 128, col0 = blockIdx.y * 128;
  gemm_core(A, Bt, row0, col0, HDH, lA, lB, acc);
  const int lane = threadIdx.x & 63, wave = threadIdx.x >> 6;
  const int wr = wave >> 1, wc = wave & 1;
#pragma unroll
  for (int m = 0; m < 4; ++m) {
    const int rbase = row0 + wr * 64 + m * 16 + (lane >> 4) * 4;
#pragma unroll
    for (int n = 0; n < 4; ++n) {
      const int col = col0 + wc * 64 + n * 16 + (lane & 15);
      const float bv = bias[col];
#pragma unroll
      for (int r = 0; r < 4; ++r)
        C[(size_t)(rbase + r) * D_ + col] = acc[m][n][r] + bv;
    }
  }
}

// ---------------- flash attention (round-18 banked: dual Q-stream + setprio) ----------------

template <bool MASKED>
__device__ __forceinline__ void softmax_pack(const f32x16& sacc, int ql, int hi,
                                             f32x16& o0, f32x16& o1,
                                             float& m, float& lsum,
                                             bf16x8& pb0v, bf16x8& pb1v) {
  float p[16];
#pragma unroll
  for (int r = 0; r < 16; ++r) {
    float s = sacc[r];
    if (MASKED) {
      const int kl = (r & 3) + 8 * (r >> 2) + 4 * hi;
      s = (kl <= ql) ? s : -1.0e30f;
    }
    p[r] = s;
  }
  float t0 = fmaxf(fmaxf(p[0], p[1]), p[2]);
  float t1 = fmaxf(fmaxf(p[3], p[4]), p[5]);
  float t2 = fmaxf(fmaxf(p[6], p[7]), p[8]);
  float t3 = fmaxf(fmaxf(p[9], p[10]), p[11]);
  float t4 = fmaxf(fmaxf(p[12], p[13]), p[14]);
  float pmax = fmaxf(fmaxf(fmaxf(t0, t1), t2), fmaxf(fmaxf(t3, t4), p[15]));
  if (__any(pmax - m > 8.0f)) {           // T13 defer-max (rare)
    const float pmr = fmaxf(pmax, __shfl_xor(pmax, 32));
    const float mn = fmaxf(m, pmr);
    const float al = __builtin_amdgcn_exp2f(m - mn);
    lsum *= al;
#pragma unroll
    for (int r = 0; r < 16; ++r) { o0[r] *= al; o1[r] *= al; }
    m = mn;
  }
#pragma unroll
  for (int r = 0; r < 16; ++r) p[r] = __builtin_amdgcn_exp2f(p[r] - m);
  {
    float s0 = (p[0] + p[1]) + (p[2] + p[3]);
    float s1 = (p[4] + p[5]) + (p[6] + p[7]);
    float s2 = (p[8] + p[9]) + (p[10] + p[11]);
    float s3 = (p[12] + p[13]) + (p[14] + p[15]);
    lsum += (s0 + s1) + (s2 + s3);
  }
  uint32_t A0 = cvt_pk_bf16(p[0],  p[1]);
  uint32_t A1 = cvt_pk_bf16(p[2],  p[3]);
  uint32_t B0 = cvt_pk_bf16(p[4],  p[5]);
  uint32_t B1 = cvt_pk_bf16(p[6],  p[7]);
  uint32_t A2 = cvt_pk_bf16(p[8],  p[9]);
  uint32_t A3 = cvt_pk_bf16(p[10], p[11]);
  uint32_t B2 = cvt_pk_bf16(p[12], p[13]);
  uint32_t B3 = cvt_pk_bf16(p[14], p[15]);
  permlane32_swap(A0, B0);
  permlane32_swap(A1, B1);
  permlane32_swap(A2, B2);
  permlane32_swap(A3, B3);
  union { uint32_t u[4]; bf16x8 v; } pb0, pb1;
  pb0.u[0] = A0; pb0.u[1] = A1; pb0.u[2] = B0; pb0.u[3] = B1;
  pb1.u[0] = A2; pb1.u[1] = A3; pb1.u[2] = B2; pb1.u[3] = B3;
  pb0v = pb0.v; pb1v = pb1.v;
}

// single-stream tile (used for stream B's solo diagonal)
template <bool MASKED>
__device__ __forceinline__ void attn_tile(int kt, int ql, int hi,
                                          const short* __restrict__ Kp,
                                          const short* __restrict__ Vp,
                                          const bf16x8 qf[4],
                                          f32x16& oacc0, f32x16& oacc1,
                                          float& m, float& lsum) {
  const short* kb = Kp + (size_t)(kt + ql) * DH_ + hi * 8;
  bf16x8 kf0 = *(const bf16x8*)(kb);
  bf16x8 kf1 = *(const bf16x8*)(kb + 16);
  bf16x8 kf2 = *(const bf16x8*)(kb + 32);
  bf16x8 kf3 = *(const bf16x8*)(kb + 48);
  const short* vb0 = Vp + (size_t)(ql) * S_ + kt + hi * 8;
  const short* vb1 = Vp + (size_t)(32 + ql) * S_ + kt + hi * 8;
  bf16x8 vf00 = *(const bf16x8*)(vb0);
  bf16x8 vf01 = *(const bf16x8*)(vb0 + 16);
  bf16x8 vf10 = *(const bf16x8*)(vb1);
  bf16x8 vf11 = *(const bf16x8*)(vb1 + 16);

  f32x16 sacc;
#pragma unroll
  for (int r = 0; r < 16; ++r) sacc[r] = 0.f;
  __builtin_amdgcn_s_setprio(1);
  sacc = __builtin_amdgcn_mfma_f32_32x32x16_bf16(kf0, qf[0], sacc, 0, 0, 0);
  sacc = __builtin_amdgcn_mfma_f32_32x32x16_bf16(kf1, qf[1], sacc, 0, 0, 0);
  sacc = __builtin_amdgcn_mfma_f32_32x32x16_bf16(kf2, qf[2], sacc, 0, 0, 0);
  sacc = __builtin_amdgcn_mfma_f32_32x32x16_bf16(kf3, qf[3], sacc, 0, 0, 0);
  __builtin_amdgcn_s_setprio(0);

  bf16x8 pb0, pb1;
  softmax_pack<MASKED>(sacc, ql, hi, oacc0, oacc1, m, lsum, pb0, pb1);

  __builtin_amdgcn_s_setprio(1);
  oacc0 = __builtin_amdgcn_mfma_f32_32x32x16_bf16(vf00, pb0, oacc0, 0, 0, 0);
  oacc0 = __builtin_amdgcn_mfma_f32_32x32x16_bf16(vf01, pb1, oacc0, 0, 0, 0);
  oacc1 = __builtin_amdgcn_mfma_f32_32x32x16_bf16(vf10, pb0, oacc1, 0, 0, 0);
  oacc1 = __builtin_amdgcn_mfma_f32_32x32x16_bf16(vf11, pb1, oacc1, 0, 0, 0);
  __builtin_amdgcn_s_setprio(0);
}

// dual-stream tile: K/V loaded once, both streams computed (A may be masked)
template <bool MASKA>
__device__ __forceinline__ void attn_tile2(int kt, int ql, int hi,
                                           const short* __restrict__ Kp,
                                           const short* __restrict__ Vp,
                                           const bf16x8 qfA[4], const bf16x8 qfB[4],
                                           f32x16& oA0, f32x16& oA1, float& mA, float& lA,
                                           f32x16& oB0, f32x16& oB1, float& mB, float& lB) {
  const short* kb = Kp + (size_t)(kt + ql) * DH_ + hi * 8;
  bf16x8 kf0 = *(const bf16x8*)(kb);
  bf16x8 kf1 = *(const bf16x8*)(kb + 16);
  bf16x8 kf2 = *(const bf16x8*)(kb + 32);
  bf16x8 kf3 = *(const bf16x8*)(kb + 48);
  const short* vb0 = Vp + (size_t)(ql) * S_ + kt + hi * 8;
  const short* vb1 = Vp + (size_t)(32 + ql) * S_ + kt + hi * 8;
  bf16x8 vf00 = *(const bf16x8*)(vb0);
  bf16x8 vf01 = *(const bf16x8*)(vb0 + 16);
  bf16x8 vf10 = *(const bf16x8*)(vb1);
  bf16x8 vf11 = *(const bf16x8*)(vb1 + 16);

  f32x16 sA, sB;
#pragma unroll
  for (int r = 0; r < 16; ++r) { sA[r] = 0.f; sB[r] = 0.f; }
  __builtin_amdgcn_s_setprio(1);
  sA = __builtin_amdgcn_mfma_f32_32x32x16_bf16(kf0, qfA[0], sA, 0, 0, 0);
  sB = __builtin_amdgcn_mfma_f32_32x32x16_bf16(kf0, qfB[0], sB, 0, 0, 0);
  sA = __builtin_amdgcn_mfma_f32_32x32x16_bf16(kf1, qfA[1], sA, 0, 0, 0);
  sB = __builtin_amdgcn_mfma_f32_32x32x16_bf16(kf1, qfB[1], sB, 0, 0, 0);
  sA = __builtin_amdgcn_mfma_f32_32x32x16_bf16(kf2, qfA[2], sA, 0, 0, 0);
  sB = __builtin_amdgcn_mfma_f32_32x32x16_bf16(kf2, qfB[2], sB, 0, 0, 0);
  sA = __builtin_amdgcn_mfma_f32_32x32x16_bf16(kf3, qfA[3], sA, 0, 0, 0);
  sB = __builtin_amdgcn_mfma_f32_32x32x16_bf16(kf3, qfB[3], sB, 0, 0, 0);
  __builtin_amdgcn_s_setprio(0);

  bf16x8 pA0, pA1, pB0, pB1;
  softmax_pack<MASKA>(sA, ql, hi, oA0, oA1, mA, lA, pA0, pA1);
  softmax_pack<false>(sB, ql, hi, oB0, oB1, mB, lB, pB0, pB1);

  __builtin_amdgcn_s_setprio(1);
  oA0 = __builtin_amdgcn_mfma_f32_32x32x16_bf16(vf00, pA0, oA0, 0, 0, 0);
  oB0 = __builtin_amdgcn_mfma_f32_32x32x16_bf16(vf00, pB0, oB0, 0, 0, 0);
  oA0 = __builtin_amdgcn_mfma_f32_32x32x16_bf16(vf01, pA1, oA0, 0, 0, 0);
  oB0 = __builtin_amdgcn_mfma_f32_32x32x16_bf16(vf01, pB1, oB0, 0, 0, 0);
  oA1 = __builtin_amdgcn_mfma_f32_32x32x16_bf16(vf10, pA0, oA1, 0, 0, 0);
  oB1 = __builtin_amdgcn_mfma_f32_32x32x16_bf16(vf10, pB0, oB1, 0, 0, 0);
  oA1 = __builtin_amdgcn_mfma_f32_32x32x16_bf16(vf11, pA1, oA1, 0, 0, 0);
  oB1 = __builtin_amdgcn_mfma_f32_32x32x16_bf16(vf11, pB1, oB1, 0, 0, 0);
  __builtin_amdgcn_s_setprio(0);
}

__device__ __forceinline__ void write_out(short* __restrict__ att, int b, int h,
                                          int q0, int ql, int hi,
                                          const f32x16& o0, const f32x16& o1, float lsum) {
  lsum += __shfl_xor(lsum, 32);
  const float rl = __builtin_amdgcn_rcpf(lsum);
  short* ob = att + (size_t)((size_t)b * S_ + q0 + ql) * HDH + h * DH_ + 4 * hi;
#pragma unroll
  for (int dt = 0; dt < 2; ++dt) {
#pragma unroll
    for (int a = 0; a < 4; ++a) {
      const int rb = 4 * a;
      float v0 = (dt ? o1[rb + 0] : o0[rb + 0]) * rl;
      float v1 = (dt ? o1[rb + 1] : o0[rb + 1]) * rl;
      float v2 = (dt ? o1[rb + 2] : o0[rb + 2]) * rl;
      float v3 = (dt ? o1[rb + 3] : o0[rb + 3]) * rl;
      short4 o;
      o.x = f2bf(v0); o.y = f2bf(v1); o.z = f2bf(v2); o.w = f2bf(v3);
      *(short4*)(ob + dt * 32 + 8 * a) = o;
    }
  }
}

// 2048 blocks x 64 threads (1 wave/block). Decode: xcd = j&7 -> bh =
// xcd+8*(c&7) (8 bh per XCD, K/V 4MB = L2); s = 31 - (c>>3) so the biggest
// pairs dispatch first and tiny pairs form the drain tail.
__global__ __launch_bounds__(64, 3) void k_attn(const short* __restrict__ Qb, const short* __restrict__ Kb,
                                                const short* __restrict__ Vt, short* __restrict__ att) {
  const int lane = threadIdx.x & 63;
  const int j = blockIdx.x;
  const int xcd = j & 7, c = j >> 3;       // c in [0,256)
  const int bhLo = c & 7;
  const int s = 31 - (c >> 3);             // 31..0, big first
  const int gg = xcd + 8 * bhLo;           // (b,h) id in [0,64)
  const int b = gg >> 4, h = gg & 15;
  const int pA = 2 * s, pB = 2 * s + 1;    // adjacent q-block pair
  const int qA = pA * 32, qB = pB * 32;
  const size_t bh = (size_t)(b * H_ + h);
  const short* Qp = Qb + bh * (S_ * DH_);
  const short* Kp = Kb + bh * (S_ * DH_);
  const short* Vp = Vt + bh * (DH_ * S_);
  const int ql = lane & 31, hi = lane >> 5;

  bf16x8 qfA[4], qfB[4];
#pragma unroll
  for (int ss = 0; ss < 4; ++ss) {
    qfA[ss] = *(const bf16x8*)(Qp + (size_t)(qA + ql) * DH_ + ss * 16 + hi * 8);
    qfB[ss] = *(const bf16x8*)(Qp + (size_t)(qB + ql) * DH_ + ss * 16 + hi * 8);
  }

  f32x16 oA0, oA1, oB0, oB1;
#pragma unroll
  for (int r = 0; r < 16; ++r) { oA0[r] = 0.f; oA1[r] = 0.f; oB0[r] = 0.f; oB1[r] = 0.f; }
  float mA = -3.0e38f, lA = 0.f, mB = -3.0e38f, lB = 0.f;

#pragma unroll 1
  for (int t = 0; t < pA; ++t)
    attn_tile2<false>(t * 32, ql, hi, Kp, Vp, qfA, qfB, oA0, oA1, mA, lA, oB0, oB1, mB, lB);
  attn_tile2<true>(qA, ql, hi, Kp, Vp, qfA, qfB, oA0, oA1, mA, lA, oB0, oB1, mB, lB);
  attn_tile<true>(qB, ql, hi, Kp, Vp, qfB, oB0, oB1, mB, lB);

  write_out(att, b, h, qA, ql, hi, oA0, oA1, lA);
  write_out(att, b, h, qB, ql, hi, oB0, oB1, lB);
}

// ---------------- launcher ----------------

extern "C" void kernel_launch(void* const* d_in, const int* in_sizes, int n_in,
                              void* d_out, int out_size, void* d_ws, size_t ws_size,
                              hipStream_t stream) {
  const float* x     = (const float*)d_in[0];
  const float* w_qkv = (const float*)d_in[1];
  const float* b_qkv = (const float*)d_in[2];
  const float* w_out = (const float*)d_in[3];
  const float* b_out = (const float*)d_in[4];
  float* out = (float*)d_out;

  char* p = (char*)d_ws;
  short* xb    = (short*)p; p += (size_t)M_TOT * D_ * 2;
  short* wqkvT = (short*)p; p += (size_t)NQKV * D_ * 2;
  short* woutT = (short*)p; p += (size_t)D_ * HDH * 2;
  short* Qb    = (short*)p; p += (size_t)B_ * H_ * S_ * DH_ * 2;
  short* Kb    = (short*)p; p += (size_t)B_ * H_ * S_ * DH_ * 2;
  short* Vt    = (short*)p; p += (size_t)B_ * H_ * S_ * DH_ * 2;
  short* att   = (short*)p; p += (size_t)M_TOT * HDH * 2;

  k_cvt<<<M_TOT * D_ / 4 / 256, 256, 0, stream>>>(x, xb, M_TOT * D_ / 4);
  k_transpose_t<<<dim3(NQKV / 32, D_ / 32), 256, 0, stream>>>(w_qkv, wqkvT, D_, NQKV);
  k_transpose_t<<<dim3(D_ / 32, HDH / 32), 256, 0, stream>>>(w_out, woutT, HDH, D_);
  k_gemm_qkv<<<dim3(M_TOT / 128, NQKV / 128), 256, 0, stream>>>(xb, wqkvT, b_qkv, Qb, Kb, Vt);
  k_attn<<<2048, 64, 0, stream>>>(Qb, Kb, Vt, att);
  k_gemm_out<<<dim3(M_TOT / 128, D_ / 128), 256, 0, stream>>>(att, woutT, b_out, out);
}

// Round 25
// 198.872 us; speedup vs baseline: 1.2805x; 1.0011x over previous
//
#include <hip/hip_runtime.h>
#include <hip/hip_bf16.h>
#include <stdint.h>

#define B_    4
#define S_    2048
#define D_    1024
#define H_    16
#define DH_   64
#define M_TOT 8192      // B*S
#define NQKV  3072      // 3*H*DH
#define HDH   1024      // H*DH

typedef __bf16 bf16_t;
typedef bf16_t bf16x8 __attribute__((ext_vector_type(8)));
typedef float  f32x4  __attribute__((ext_vector_type(4)));
typedef float  f32x16 __attribute__((ext_vector_type(16)));

// scale folded into Q at QKV epilogue: 1/sqrt(64) * log2(e)
#define QSCALE 0.1803368801111204f

__device__ __forceinline__ short f2bf(float f) {
  union { float f; uint32_t u; } x; x.f = f;
  uint32_t r = (x.u + 0x7fffu + ((x.u >> 16) & 1u)) >> 16;
  return (short)(uint16_t)r;
}

__device__ __forceinline__ uint32_t cvt_pk_bf16(float lo, float hi) {
  uint32_t r;
  asm("v_cvt_pk_bf16_f32 %0, %1, %2" : "=v"(r) : "v"(lo), "v"(hi));
  return r;
}

// d' = {d.lo, s.lo}, s' = {d.hi, s.hi}
__device__ __forceinline__ void permlane32_swap(uint32_t& d, uint32_t& s) {
  asm("v_permlane32_swap_b32 %0, %1" : "+v"(d), "+v"(s));
}

#define ASYNC_COPY16(g, l) \
  __builtin_amdgcn_global_load_lds((const __attribute__((address_space(1))) void*)(g), \
                                   (__attribute__((address_space(3))) void*)(l), 16, 0, 0)

// ---------------- prep kernels ----------------

__global__ __launch_bounds__(256) void k_cvt(const float* __restrict__ in, short* __restrict__ out, int n4) {
  int i = blockIdx.x * 256 + threadIdx.x;
  if (i < n4) {
    float4 v = ((const float4*)in)[i];
    short4 o;
    o.x = f2bf(v.x); o.y = f2bf(v.y); o.z = f2bf(v.z); o.w = f2bf(v.w);
    ((short4*)out)[i] = o;
  }
}

// LDS-tiled transpose: in (R,C) f32 row-major -> out (C,R) bf16 row-major.
__global__ __launch_bounds__(256) void k_transpose_t(const float* __restrict__ in, short* __restrict__ out,
                                                     int R, int C) {
  __shared__ short t[32][33];
  const int bx = blockIdx.x * 32;
  const int by = blockIdx.y * 32;
  const int tid = threadIdx.x;
  const int row = tid >> 3, c4 = (tid & 7) * 4;
  const float4 v = *(const float4*)&in[(size_t)(by + row) * C + bx + c4];
  t[row][c4 + 0] = f2bf(v.x); t[row][c4 + 1] = f2bf(v.y);
  t[row][c4 + 2] = f2bf(v.z); t[row][c4 + 3] = f2bf(v.w);
  __syncthreads();
  short4 o;
  o.x = t[c4 + 0][row]; o.y = t[c4 + 1][row];
  o.z = t[c4 + 2][row]; o.w = t[c4 + 3][row];
  *(short4*)&out[(size_t)(bx + row) * R + by + c4] = o;
}

// ---------------- GEMM core: C = A(row-major MxK) * Bt(row-major NxK)^T ----------------
// Round-13 proven 2-barrier BK=32 structure.

__device__ __forceinline__ void gemm_core(const short* __restrict__ A,
                                          const short* __restrict__ Bt,
                                          int row0, int col0, int K,
                                          short* lA, short* lB,
                                          f32x4 acc[4][4]) {
  const int tid  = threadIdx.x;
  const int wave = tid >> 6, lane = tid & 63;
  const int wr = wave >> 1, wc = wave & 1;
  const int stg_r = lane >> 2;
  const int stg_k = (lane & 3) * 8;
  const int fr = lane & 15;
  const int fk = (lane >> 4) * 8;

  for (int k0 = 0; k0 < K; k0 += 32) {
    __syncthreads();
#pragma unroll
    for (int c = 0; c < 2; ++c) {
      const int seg = wave * 2 + c;
      const short* ga = A  + (size_t)(row0 + seg * 16 + stg_r) * K + (k0 + stg_k);
      const short* gb = Bt + (size_t)(col0 + seg * 16 + stg_r) * K + (k0 + stg_k);
      ASYNC_COPY16(ga, lA + seg * 512);
      ASYNC_COPY16(gb, lB + seg * 512);
    }
    __syncthreads();
    bf16x8 af[4], bfr[4];
#pragma unroll
    for (int m = 0; m < 4; ++m)
      af[m] = *(const bf16x8*)(lA + (wr * 64 + m * 16 + fr) * 32 + fk);
#pragma unroll
    for (int n = 0; n < 4; ++n)
      bfr[n] = *(const bf16x8*)(lB + (wc * 64 + n * 16 + fr) * 32 + fk);
#pragma unroll
    for (int m = 0; m < 4; ++m)
#pragma unroll
      for (int n = 0; n < 4; ++n)
        acc[m][n] = __builtin_amdgcn_mfma_f32_16x16x32_bf16(af[m], bfr[n], acc[m][n], 0, 0, 0);
  }
}

// QKV GEMM epilogue scatters to Q (scaled), K, Vt with bias add. 2-D grid.
// Vt writes packed as short4 (r -> s contiguous, same bb/hh/e; 8B-aligned).
__global__ __launch_bounds__(256) void k_gemm_qkv(const short* __restrict__ A, const short* __restrict__ Bt,
                                                  const float* __restrict__ bias,
                                                  short* __restrict__ Qb, short* __restrict__ Kb,
                                                  short* __restrict__ Vt) {
  __shared__ short lA[128 * 32];
  __shared__ short lB[128 * 32];
  f32x4 acc[4][4];
#pragma unroll
  for (int m = 0; m < 4; ++m)
#pragma unroll
    for (int n = 0; n < 4; ++n)
      acc[m][n] = (f32x4){0.f, 0.f, 0.f, 0.f};
  const int row0 = blockIdx.x * 128, col0 = blockIdx.y * 128;
  gemm_core(A, Bt, row0, col0, D_, lA, lB, acc);
  const int lane = threadIdx.x & 63, wave = threadIdx.x >> 6;
  const int wr = wave >> 1, wc = wave & 1;
#pragma unroll
  for (int m = 0; m < 4; ++m) {
    const int rbase = row0 + wr * 64 + m * 16 + (lane >> 4) * 4;
    const int bb = rbase >> 11, s0 = rbase & 2047;   // row-quad stays in one b
#pragma unroll
    for (int n = 0; n < 4; ++n) {
      const int col = col0 + wc * 64 + n * 16 + (lane & 15);
      const float bv = bias[col];
      const int t = col >> 10, rem = col & 1023, hh = rem >> 6, e = rem & 63;
      if (t == 2) {
        short4 o;
        o.x = f2bf(acc[m][n][0] + bv);
        o.y = f2bf(acc[m][n][1] + bv);
        o.z = f2bf(acc[m][n][2] + bv);
        o.w = f2bf(acc[m][n][3] + bv);
        *(short4*)&Vt[((size_t)(bb * H_ + hh) * DH_ + e) * S_ + s0] = o;
      } else if (t == 0) {
#pragma unroll
        for (int r = 0; r < 4; ++r)
          Qb[((size_t)(bb * H_ + hh) * S_ + (s0 + r)) * DH_ + e] = f2bf((acc[m][n][r] + bv) * QSCALE);
      } else {
#pragma unroll
        for (int r = 0; r < 4; ++r)
          Kb[((size_t)(bb * H_ + hh) * S_ + (s0 + r)) * DH_ + e] = f2bf(acc[m][n][r] + bv);
      }
    }
  }
}

// Output GEMM: out f32 + bias. 2-D grid (64, 8).
__global__ __launch_bounds__(256) void k_gemm_out(const short* __restrict__ A, const short* __restrict__ Bt,
                                                  const float* __restrict__ bias, float* __restrict__ C) {
  __shared__ short lA[128 * 32];
  __shared__ short lB[128 * 32];
  f32x4 acc[4][4];
#pragma unroll
  for (int m = 0; m < 4; ++m)
#pragma unroll
    for (int n = 0; n < 4; ++n)
      acc[m][n] = (f32x4){0.f, 0.f, 0.f, 0.f};
  const int row0 = blockIdx.x * 128, col0 = blockIdx.y * 128;
  gemm_core(A, Bt, row0, col0, HDH, lA, lB, acc);
  const int lane = threadIdx.x & 63, wave = threadIdx.x >> 6;
  const int wr = wave >> 1, wc = wave & 1;
#pragma unroll
  for (int m = 0; m < 4; ++m) {
    const int rbase = row0 + wr * 64 + m * 16 + (lane >> 4) * 4;
#pragma unroll
    for (int n = 0; n < 4; ++n) {
      const int col = col0 + wc * 64 + n * 16 + (lane & 15);
      const float bv = bias[col];
#pragma unroll
      for (int r = 0; r < 4; ++r)
        C[(size_t)(rbase + r) * D_ + col] = acc[m][n][r] + bv;
    }
  }
}

// ---------------- flash attention (dual Q-stream + setprio; unroll-2 K-loop) ----------------

template <bool MASKED>
__device__ __forceinline__ void softmax_pack(const f32x16& sacc, int ql, int hi,
                                             f32x16& o0, f32x16& o1,
                                             float& m, float& lsum,
                                             bf16x8& pb0v, bf16x8& pb1v) {
  float p[16];
#pragma unroll
  for (int r = 0; r < 16; ++r) {
    float s = sacc[r];
    if (MASKED) {
      const int kl = (r & 3) + 8 * (r >> 2) + 4 * hi;
      s = (kl <= ql) ? s : -1.0e30f;
    }
    p[r] = s;
  }
  float t0 = fmaxf(fmaxf(p[0], p[1]), p[2]);
  float t1 = fmaxf(fmaxf(p[3], p[4]), p[5]);
  float t2 = fmaxf(fmaxf(p[6], p[7]), p[8]);
  float t3 = fmaxf(fmaxf(p[9], p[10]), p[11]);
  float t4 = fmaxf(fmaxf(p[12], p[13]), p[14]);
  float pmax = fmaxf(fmaxf(fmaxf(t0, t1), t2), fmaxf(fmaxf(t3, t4), p[15]));
  if (__any(pmax - m > 8.0f)) {           // T13 defer-max (rare)
    const float pmr = fmaxf(pmax, __shfl_xor(pmax, 32));
    const float mn = fmaxf(m, pmr);
    const float al = __builtin_amdgcn_exp2f(m - mn);
    lsum *= al;
#pragma unroll
    for (int r = 0; r < 16; ++r) { o0[r] *= al; o1[r] *= al; }
    m = mn;
  }
#pragma unroll
  for (int r = 0; r < 16; ++r) p[r] = __builtin_amdgcn_exp2f(p[r] - m);
  {
    float s0 = (p[0] + p[1]) + (p[2] + p[3]);
    float s1 = (p[4] + p[5]) + (p[6] + p[7]);
    float s2 = (p[8] + p[9]) + (p[10] + p[11]);
    float s3 = (p[12] + p[13]) + (p[14] + p[15]);
    lsum += (s0 + s1) + (s2 + s3);
  }
  uint32_t A0 = cvt_pk_bf16(p[0],  p[1]);
  uint32_t A1 = cvt_pk_bf16(p[2],  p[3]);
  uint32_t B0 = cvt_pk_bf16(p[4],  p[5]);
  uint32_t B1 = cvt_pk_bf16(p[6],  p[7]);
  uint32_t A2 = cvt_pk_bf16(p[8],  p[9]);
  uint32_t A3 = cvt_pk_bf16(p[10], p[11]);
  uint32_t B2 = cvt_pk_bf16(p[12], p[13]);
  uint32_t B3 = cvt_pk_bf16(p[14], p[15]);
  permlane32_swap(A0, B0);
  permlane32_swap(A1, B1);
  permlane32_swap(A2, B2);
  permlane32_swap(A3, B3);
  union { uint32_t u[4]; bf16x8 v; } pb0, pb1;
  pb0.u[0] = A0; pb0.u[1] = A1; pb0.u[2] = B0; pb0.u[3] = B1;
  pb1.u[0] = A2; pb1.u[1] = A3; pb1.u[2] = B2; pb1.u[3] = B3;
  pb0v = pb0.v; pb1v = pb1.v;
}

// single-stream tile (used for stream B's solo diagonal)
template <bool MASKED>
__device__ __forceinline__ void attn_tile(int kt, int ql, int hi,
                                          const short* __restrict__ Kp,
                                          const short* __restrict__ Vp,
                                          const bf16x8 qf[4],
                                          f32x16& oacc0, f32x16& oacc1,
                                          float& m, float& lsum) {
  const short* kb = Kp + (size_t)(kt + ql) * DH_ + hi * 8;
  bf16x8 kf0 = *(const bf16x8*)(kb);
  bf16x8 kf1 = *(const bf16x8*)(kb + 16);
  bf16x8 kf2 = *(const bf16x8*)(kb + 32);
  bf16x8 kf3 = *(const bf16x8*)(kb + 48);
  const short* vb0 = Vp + (size_t)(ql) * S_ + kt + hi * 8;
  const short* vb1 = Vp + (size_t)(32 + ql) * S_ + kt + hi * 8;
  bf16x8 vf00 = *(const bf16x8*)(vb0);
  bf16x8 vf01 = *(const bf16x8*)(vb0 + 16);
  bf16x8 vf10 = *(const bf16x8*)(vb1);
  bf16x8 vf11 = *(const bf16x8*)(vb1 + 16);

  f32x16 sacc;
#pragma unroll
  for (int r = 0; r < 16; ++r) sacc[r] = 0.f;
  __builtin_amdgcn_s_setprio(1);
  sacc = __builtin_amdgcn_mfma_f32_32x32x16_bf16(kf0, qf[0], sacc, 0, 0, 0);
  sacc = __builtin_amdgcn_mfma_f32_32x32x16_bf16(kf1, qf[1], sacc, 0, 0, 0);
  sacc = __builtin_amdgcn_mfma_f32_32x32x16_bf16(kf2, qf[2], sacc, 0, 0, 0);
  sacc = __builtin_amdgcn_mfma_f32_32x32x16_bf16(kf3, qf[3], sacc, 0, 0, 0);
  __builtin_amdgcn_s_setprio(0);

  bf16x8 pb0, pb1;
  softmax_pack<MASKED>(sacc, ql, hi, oacc0, oacc1, m, lsum, pb0, pb1);

  __builtin_amdgcn_s_setprio(1);
  oacc0 = __builtin_amdgcn_mfma_f32_32x32x16_bf16(vf00, pb0, oacc0, 0, 0, 0);
  oacc0 = __builtin_amdgcn_mfma_f32_32x32x16_bf16(vf01, pb1, oacc0, 0, 0, 0);
  oacc1 = __builtin_amdgcn_mfma_f32_32x32x16_bf16(vf10, pb0, oacc1, 0, 0, 0);
  oacc1 = __builtin_amdgcn_mfma_f32_32x32x16_bf16(vf11, pb1, oacc1, 0, 0, 0);
  __builtin_amdgcn_s_setprio(0);
}

// dual-stream tile: K/V loaded once, both streams computed (A may be masked)
template <bool MASKA>
__device__ __forceinline__ void attn_tile2(int kt, int ql, int hi,
                                           const short* __restrict__ Kp,
                                           const short* __restrict__ Vp,
                                           const bf16x8 qfA[4], const bf16x8 qfB[4],
                                           f32x16& oA0, f32x16& oA1, float& mA, float& lA,
                                           f32x16& oB0, f32x16& oB1, float& mB, float& lB) {
  const short* kb = Kp + (size_t)(kt + ql) * DH_ + hi * 8;
  bf16x8 kf0 = *(const bf16x8*)(kb);
  bf16x8 kf1 = *(const bf16x8*)(kb + 16);
  bf16x8 kf2 = *(const bf16x8*)(kb + 32);
  bf16x8 kf3 = *(const bf16x8*)(kb + 48);
  const short* vb0 = Vp + (size_t)(ql) * S_ + kt + hi * 8;
  const short* vb1 = Vp + (size_t)(32 + ql) * S_ + kt + hi * 8;
  bf16x8 vf00 = *(const bf16x8*)(vb0);
  bf16x8 vf01 = *(const bf16x8*)(vb0 + 16);
  bf16x8 vf10 = *(const bf16x8*)(vb1);
  bf16x8 vf11 = *(const bf16x8*)(vb1 + 16);

  f32x16 sA, sB;
#pragma unroll
  for (int r = 0; r < 16; ++r) { sA[r] = 0.f; sB[r] = 0.f; }
  __builtin_amdgcn_s_setprio(1);
  sA = __builtin_amdgcn_mfma_f32_32x32x16_bf16(kf0, qfA[0], sA, 0, 0, 0);
  sB = __builtin_amdgcn_mfma_f32_32x32x16_bf16(kf0, qfB[0], sB, 0, 0, 0);
  sA = __builtin_amdgcn_mfma_f32_32x32x16_bf16(kf1, qfA[1], sA, 0, 0, 0);
  sB = __builtin_amdgcn_mfma_f32_32x32x16_bf16(kf1, qfB[1], sB, 0, 0, 0);
  sA = __builtin_amdgcn_mfma_f32_32x32x16_bf16(kf2, qfA[2], sA, 0, 0, 0);
  sB = __builtin_amdgcn_mfma_f32_32x32x16_bf16(kf2, qfB[2], sB, 0, 0, 0);
  sA = __builtin_amdgcn_mfma_f32_32x32x16_bf16(kf3, qfA[3], sA, 0, 0, 0);
  sB = __builtin_amdgcn_mfma_f32_32x32x16_bf16(kf3, qfB[3], sB, 0, 0, 0);
  __builtin_amdgcn_s_setprio(0);

  bf16x8 pA0, pA1, pB0, pB1;
  softmax_pack<MASKA>(sA, ql, hi, oA0, oA1, mA, lA, pA0, pA1);
  softmax_pack<false>(sB, ql, hi, oB0, oB1, mB, lB, pB0, pB1);

  __builtin_amdgcn_s_setprio(1);
  oA0 = __builtin_amdgcn_mfma_f32_32x32x16_bf16(vf00, pA0, oA0, 0, 0, 0);
  oB0 = __builtin_amdgcn_mfma_f32_32x32x16_bf16(vf00, pB0, oB0, 0, 0, 0);
  oA0 = __builtin_amdgcn_mfma_f32_32x32x16_bf16(vf01, pA1, oA0, 0, 0, 0);
  oB0 = __builtin_amdgcn_mfma_f32_32x32x16_bf16(vf01, pB1, oB0, 0, 0, 0);
  oA1 = __builtin_amdgcn_mfma_f32_32x32x16_bf16(vf10, pA0, oA1, 0, 0, 0);
  oB1 = __builtin_amdgcn_mfma_f32_32x32x16_bf16(vf10, pB0, oB1, 0, 0, 0);
  oA1 = __builtin_amdgcn_mfma_f32_32x32x16_bf16(vf11, pA1, oA1, 0, 0, 0);
  oB1 = __builtin_amdgcn_mfma_f32_32x32x16_bf16(vf11, pB1, oB1, 0, 0, 0);
  __builtin_amdgcn_s_setprio(0);
}

__device__ __forceinline__ void write_out(short* __restrict__ att, int b, int h,
                                          int q0, int ql, int hi,
                                          const f32x16& o0, const f32x16& o1, float lsum) {
  lsum += __shfl_xor(lsum, 32);
  const float rl = __builtin_amdgcn_rcpf(lsum);
  short* ob = att + (size_t)((size_t)b * S_ + q0 + ql) * HDH + h * DH_ + 4 * hi;
#pragma unroll
  for (int dt = 0; dt < 2; ++dt) {
#pragma unroll
    for (int a = 0; a < 4; ++a) {
      const int rb = 4 * a;
      float v0 = (dt ? o1[rb + 0] : o0[rb + 0]) * rl;
      float v1 = (dt ? o1[rb + 1] : o0[rb + 1]) * rl;
      float v2 = (dt ? o1[rb + 2] : o0[rb + 2]) * rl;
      float v3 = (dt ? o1[rb + 3] : o0[rb + 3]) * rl;
      short4 o;
      o.x = f2bf(v0); o.y = f2bf(v1); o.z = f2bf(v2); o.w = f2bf(v3);
      *(short4*)(ob + dt * 32 + 8 * a) = o;
    }
  }
}

// 2048 blocks x 64 threads (1 wave/block). Decode: xcd = j&7 -> bh =
// xcd+8*(c&7) (8 bh per XCD, K/V 4MB = L2); s = 31 - (c>>3) so the biggest
// pairs dispatch first and tiny pairs form the drain tail. K-loop unroll 2:
// lets the COMPILER hoist next-tile K/V loads under current-tile compute at
// its discretion (no loop-carried temps -> no forced spill, unlike r16/r17).
__global__ __launch_bounds__(64, 3) void k_attn(const short* __restrict__ Qb, const short* __restrict__ Kb,
                                                const short* __restrict__ Vt, short* __restrict__ att) {
  const int lane = threadIdx.x & 63;
  const int j = blockIdx.x;
  const int xcd = j & 7, c = j >> 3;       // c in [0,256)
  const int bhLo = c & 7;
  const int s = 31 - (c >> 3);             // 31..0, big first
  const int gg = xcd + 8 * bhLo;           // (b,h) id in [0,64)
  const int b = gg >> 4, h = gg & 15;
  const int pA = 2 * s, pB = 2 * s + 1;    // adjacent q-block pair
  const int qA = pA * 32, qB = pB * 32;
  const size_t bh = (size_t)(b * H_ + h);
  const short* Qp = Qb + bh * (S_ * DH_);
  const short* Kp = Kb + bh * (S_ * DH_);
  const short* Vp = Vt + bh * (DH_ * S_);
  const int ql = lane & 31, hi = lane >> 5;

  bf16x8 qfA[4], qfB[4];
#pragma unroll
  for (int ss = 0; ss < 4; ++ss) {
    qfA[ss] = *(const bf16x8*)(Qp + (size_t)(qA + ql) * DH_ + ss * 16 + hi * 8);
    qfB[ss] = *(const bf16x8*)(Qp + (size_t)(qB + ql) * DH_ + ss * 16 + hi * 8);
  }

  f32x16 oA0, oA1, oB0, oB1;
#pragma unroll
  for (int r = 0; r < 16; ++r) { oA0[r] = 0.f; oA1[r] = 0.f; oB0[r] = 0.f; oB1[r] = 0.f; }
  float mA = -3.0e38f, lA = 0.f, mB = -3.0e38f, lB = 0.f;

#pragma unroll 2
  for (int t = 0; t < pA; ++t)
    attn_tile2<false>(t * 32, ql, hi, Kp, Vp, qfA, qfB, oA0, oA1, mA, lA, oB0, oB1, mB, lB);
  attn_tile2<true>(qA, ql, hi, Kp, Vp, qfA, qfB, oA0, oA1, mA, lA, oB0, oB1, mB, lB);
  attn_tile<true>(qB, ql, hi, Kp, Vp, qfB, oB0, oB1, mB, lB);

  write_out(att, b, h, qA, ql, hi, oA0, oA1, lA);
  write_out(att, b, h, qB, ql, hi, oB0, oB1, lB);
}

// ---------------- launcher ----------------

extern "C" void kernel_launch(void* const* d_in, const int* in_sizes, int n_in,
                              void* d_out, int out_size, void* d_ws, size_t ws_size,
                              hipStream_t stream) {
  const float* x     = (const float*)d_in[0];
  const float* w_qkv = (const float*)d_in[1];
  const float* b_qkv = (const float*)d_in[2];
  const float* w_out = (const float*)d_in[3];
  const float* b_out = (const float*)d_in[4];
  float* out = (float*)d_out;

  char* p = (char*)d_ws;
  short* xb    = (short*)p; p += (size_t)M_TOT * D_ * 2;
  short* wqkvT = (short*)p; p += (size_t)NQKV * D_ * 2;
  short* woutT = (short*)p; p += (size_t)D_ * HDH * 2;
  short* Qb    = (short*)p; p += (size_t)B_ * H_ * S_ * DH_ * 2;
  short* Kb    = (short*)p; p += (size_t)B_ * H_ * S_ * DH_ * 2;
  short* Vt    = (short*)p; p += (size_t)B_ * H_ * S_ * DH_ * 2;
  short* att   = (short*)p; p += (size_t)M_TOT * HDH * 2;

  k_cvt<<<M_TOT * D_ / 4 / 256, 256, 0, stream>>>(x, xb, M_TOT * D_ / 4);
  k_transpose_t<<<dim3(NQKV / 32, D_ / 32), 256, 0, stream>>>(w_qkv, wqkvT, D_, NQKV);
  k_transpose_t<<<dim3(D_ / 32, HDH / 32), 256, 0, stream>>>(w_out, woutT, HDH, D_);
  k_gemm_qkv<<<dim3(M_TOT / 128, NQKV / 128), 256, 0, stream>>>(xb, wqkvT, b_qkv, Qb, Kb, Vt);
  k_attn<<<2048, 64, 0, stream>>>(Qb, Kb, Vt, att);
  k_gemm_out<<<dim3(M_TOT / 128, D_ / 128), 256, 0, stream>>>(att, woutT, b_out, out);
}